// Round 5
// baseline (286.369 us; speedup 1.0000x reference)
//
#include <hip/hip_runtime.h>
#include <hip/hip_bf16.h>

#define NTOK 49
#define CDIM 128
#define SCALE 0.17677669529663687f

// packed table sizes (elements)
#define CMB_ELEMS (64*4*4*16*4*16)    // 1048576 f32 [w][h][ct][ln][quad][rt][r] = mask+rpb (+pad)
#define PWQK_ELEMS  (4*4*4*4*16*8)    // 32768 bf16  [h][rt][ks][quad][ln][j]  (A-frags of Wq/Wk^T)
#define PV_ELEMS    (8*4*4*16*8)      // 16384 bf16  [c2][ks][quad][ln][j]     (B-frags of Wv)
#define PWP_ELEMS   (8*4*4*16*8)      // 16384 bf16  [rt][ks][quad][ln][j]     (A-frags of Wproj^T)

// LDS layout (units: shorts), per head region HSZ = 4608:
//   q[n 0..63][d stride QS=36] @0 ; k @KOFFS=2304 ; P[n][m stride PS=68] aliases q+k (4352<=4608)
//   v^T[d 0..31][m stride VS=68] written into rows 0..31 AFTER all P reads (v held in regs until then)
//   O-slice[n<56][c-in-head stride OS=36] overwrites v^T/P after their reads
// All per-wave aliasing relies on in-order DS within a wave (no barriers needed).
// Strides 36/68 (stride/2 ≡ 2 mod 4): measured 0 bank conflicts on this pattern.
//
// History:
//   r1: 2 blocks/CU (21% occ), 144 us      r2: (256,4) -> spills -> 185 us
//   r3: per-ct softmax, 3 blocks (31%), 158 us (ILP loss)
//   r4: ct-pair softmax + pre-summed mask+rpb table: 141 us.  KEY FACT: occupancy
//       21%->30% bought only 2% -> win_attn is NOT wave-starved; micro-tweaks plateaued.
//   r5 (this): win_attn UNTOUCHED. Attack the other ~140 us: prep_kernel was 1.3M threads
//       of uncoalesced global gathers (stride-196B mask reads + rel->bias double gather).
//       Rewrite: LDS-staged per-(w,h) blocks, coalesced in/out.
#define QS 36
#define PS 68
#define VS 68
#define OS 36
#define KOFFS (64*QS)          // 2304
#define HSZ   (2*KOFFS)        // 4608
#define LDS_SH (4*HSZ)         // 18432 shorts = 36864 B; 3 blocks -> 110 KB <= 160 KB

typedef __attribute__((ext_vector_type(8))) __bf16 bf16x8;
typedef __attribute__((ext_vector_type(4))) float f32x4;

__device__ __forceinline__ unsigned short f2bf(float f) {
  unsigned int u = __float_as_uint(f);
  u += 0x7fffu + ((u >> 16) & 1u);   // RTNE
  return (unsigned short)(u >> 16);
}

__device__ __forceinline__ unsigned int pk2(float a, float b) {
  union { __hip_bfloat162 h2; unsigned int u; } r;
  r.h2 = __float22bfloat162_rn(make_float2(a, b));
  return r.u;
}
__device__ __forceinline__ unsigned long long pk4(float a, float b, float c, float d) {
  return (unsigned long long)pk2(a, b) | ((unsigned long long)pk2(c, d) << 32);
}
__device__ __forceinline__ bf16x8 pack8(float4 a, float4 b) {
  union { bf16x8 v; unsigned int u[4]; } r;
  r.u[0] = pk2(a.x, a.y); r.u[1] = pk2(a.z, a.w);
  r.u[2] = pk2(b.x, b.y); r.u[3] = pk2(b.z, b.w);
  return r.v;
}
// two ds_read_b64 (rows are 8B- but not 16B-aligned)
__device__ __forceinline__ bf16x8 ld8(const unsigned short* p) {
  union { bf16x8 v; unsigned long long q[2]; } r;
  r.q[0] = *(const unsigned long long*)(p);
  r.q[1] = *(const unsigned long long*)(p + 4);
  return r.v;
}

// ---- prep: LDS-staged cmb build (blocks 0..255) + weight fragments (blocks 256..511) ----
__global__ __launch_bounds__(256) void prep_kernel(
    const float* __restrict__ mask,
    const float* __restrict__ qkv_w,
    const float* __restrict__ proj_w,
    const float* __restrict__ bias_table,
    const int* __restrict__ rel_index,
    float* __restrict__ cmb,
    unsigned short* __restrict__ pwqk,
    unsigned short* __restrict__ pv,
    unsigned short* __restrict__ pwp) {
  const int t = threadIdx.x;
  if (blockIdx.x < 256) {
    // one block per (w, h): stage mask slab (contiguous), rel_index, bias_table in LDS;
    // compute 4096 swizzled outputs from LDS gathers; coalesced writes.
    __shared__ float sm[NTOK * NTOK];
    __shared__ int   sri[NTOK * NTOK];
    __shared__ float sbt[169 * 4];
    const int w = blockIdx.x >> 2;
    const int h = blockIdx.x & 3;
    const float* mw = mask + (size_t)w * (NTOK * NTOK);
    for (int i = t; i < NTOK * NTOK; i += 256) { sm[i] = mw[i]; sri[i] = rel_index[i]; }
    for (int i = t; i < 169 * 4; i += 256) sbt[i] = bias_table[i];
    __syncthreads();
    float* cw = cmb + ((size_t)w * 4 + h) * 4096;
    #pragma unroll
    for (int o0 = 0; o0 < 4096; o0 += 256) {
      const int o = o0 + t;
      // o bits: r(0-1) rt(2-3) quad(4-5) ln(6-9) ct(10-11)
      const int r = o & 3, rt = (o >> 2) & 3, quad = (o >> 4) & 3,
                ln = (o >> 6) & 15, ct = (o >> 10) & 3;
      const int n = ct * 16 + ln;
      const int m = rt * 16 + quad * 4 + r;
      float v;
      if (m >= NTOK)      v = -1e30f;   // masked rows: exp -> 0
      else if (n >= NTOK) v = 0.0f;     // pad cols: outputs discarded later
      else {
        const int idx = n * NTOK + m;
        v = sm[idx] + sbt[sri[idx] * 4 + h];
      }
      cw[o] = v;
    }
    return;
  }
  // weight fragments: 65536 elements, one per thread
  int i = (blockIdx.x - 256) * 256 + t;
  if (i < PWQK_ELEMS) {
    int j = i & 7, ln = (i >> 3) & 15, quad = (i >> 7) & 3, ks = (i >> 9) & 3,
        rt = (i >> 11) & 3, h = (i >> 13) & 3;
    int kk  = ks * 32 + quad * 8 + j;
    int col = (rt < 2) ? (h * 32 + rt * 16 + ln) : (128 + h * 32 + (rt - 2) * 16 + ln);
    pwqk[i] = f2bf(qkv_w[kk * 384 + col]);
    return;
  }
  i -= PWQK_ELEMS;
  if (i < PV_ELEMS) {
    int j = i & 7, ln = (i >> 3) & 15, quad = (i >> 7) & 3, ks = (i >> 9) & 3, c2 = (i >> 11) & 7;
    pv[i] = f2bf(qkv_w[(ks * 32 + quad * 8 + j) * 384 + 256 + c2 * 16 + ln]);
    return;
  }
  i -= PV_ELEMS;
  if (i < PWP_ELEMS) {
    int j = i & 7, ln = (i >> 3) & 15, quad = (i >> 7) & 3, ks = (i >> 9) & 3, rt = (i >> 11) & 7;
    pwp[i] = f2bf(proj_w[(ks * 32 + quad * 8 + j) * 128 + rt * 16 + ln]);
  }
}

// ---- fused window attention: 1 block = 1 window, wave h owns head h; ONE barrier total ----
__global__ __launch_bounds__(256, 3) void win_attn_kernel(
    const float* __restrict__ x,
    const float* __restrict__ qkv_b,
    const float* __restrict__ proj_b,
    const float* __restrict__ cmb,
    const unsigned short* __restrict__ pwqk,
    const unsigned short* __restrict__ pv,
    const unsigned short* __restrict__ pwp,
    float* __restrict__ out)
{
  __shared__ alignas(16) unsigned short lds[LDS_SH];

  const int b    = blockIdx.x;
  const int tid  = threadIdx.x;
  const int h    = tid >> 6;
  const int lane = tid & 63;
  const int ln   = lane & 15;
  const int quad = lane >> 4;

  unsigned short* hb = lds + h * HSZ;

  // ---- x fragments from global: serve as A (rows=tokens) for v-GEMM and B (cols=tokens) for q/k ----
  bf16x8 afr[4][4];
  {
    const float* xb = x + (size_t)b * (NTOK * CDIM);
    #pragma unroll
    for (int rt = 0; rt < 4; rt++) {
      const int row = rt * 16 + ln;
      #pragma unroll
      for (int ks = 0; ks < 4; ks++) {
        if (row < NTOK) {
          const float* p = xb + row * CDIM + ks * 32 + quad * 8;
          afr[rt][ks] = pack8(*(const float4*)p, *(const float4*)(p + 4));
        } else {
          union { bf16x8 v; unsigned int u[4]; } z;
          z.u[0] = z.u[1] = z.u[2] = z.u[3] = 0u;
          afr[rt][ks] = z.v;   // pad tokens -> 0; downstream q/k/v pad entries = bias (finite)
        }
      }
    }
  }

  // ---------------- stage A-v: v = x @ Wv; result HELD in regs (hv), no LDS yet ----------------
  unsigned long long hv[2][4];   // [ci: d-tile][mt: m-tile] packed 4x bf16 (m = mt*16+quad*4+r)
  #pragma unroll
  for (int ci = 0; ci < 2; ci++) {
    bf16x8 bvf[4];
    #pragma unroll
    for (int ks = 0; ks < 4; ks++)
      bvf[ks] = *(const bf16x8*)&pv[((((h*2 + ci)*4 + ks)*4 + quad)*16 + ln)*8];
    const float bvb = qkv_b[256 + (h*2 + ci)*16 + ln];
    f32x4 acc[4];
    #pragma unroll
    for (int rt = 0; rt < 4; rt++) { f32x4 bi = {bvb, bvb, bvb, bvb}; acc[rt] = bi; }
    #pragma unroll
    for (int ks = 0; ks < 4; ks++)
      #pragma unroll
      for (int rt = 0; rt < 4; rt++)
        acc[rt] = __builtin_amdgcn_mfma_f32_16x16x32_bf16(afr[rt][ks], bvf[ks], acc[rt], 0, 0, 0);
    // C: row=token m (quad*4+r), col=d (ln)  -> pack v^T[d][m] quadruples, keep in regs
    #pragma unroll
    for (int rt = 0; rt < 4; rt++)
      hv[ci][rt] = pk4(acc[rt][0], acc[rt][1], acc[rt][2], acc[rt][3]);
  }

  // ---------------- stage A-qk: qkv^T = W^T @ x^T (C rows=features) ----------------
  #pragma unroll
  for (int rt = 0; rt < 4; rt++) {
    bf16x8 awf[4];
    #pragma unroll
    for (int ks = 0; ks < 4; ks++)
      awf[ks] = *(const bf16x8*)&pwqk[((((h*4 + rt)*4 + ks)*4 + quad)*16 + ln)*8];
    const int fb = (rt < 2) ? (h*32 + rt*16 + quad*4) : (128 + h*32 + (rt - 2)*16 + quad*4);
    const float4 qb4 = *(const float4*)&qkv_b[fb];
    f32x4 acc2[4];
    #pragma unroll
    for (int ct = 0; ct < 4; ct++) { f32x4 bi = {qb4.x, qb4.y, qb4.z, qb4.w}; acc2[ct] = bi; }
    #pragma unroll
    for (int ks = 0; ks < 4; ks++)
      #pragma unroll
      for (int ct = 0; ct < 4; ct++)
        acc2[ct] = __builtin_amdgcn_mfma_f32_16x16x32_bf16(awf[ks], afr[ct][ks], acc2[ct], 0, 0, 0);
    // C: row=feature (quad*4+r), col=token n (ln) -> q[n][d] / k[m][d], d r-consecutive -> b64
    const int base = (rt < 2) ? 0 : KOFFS;
    const int d0   = (rt < 2) ? (rt*16 + quad*4) : ((rt - 2)*16 + quad*4);
    const float sc = (rt < 2) ? SCALE : 1.0f;   // fold softmax scale into q
    #pragma unroll
    for (int ct = 0; ct < 4; ct++)
      *(unsigned long long*)&hb[base + (ct*16 + ln)*QS + d0] =
          pk4(acc2[ct][0]*sc, acc2[ct][1]*sc, acc2[ct][2]*sc, acc2[ct][3]*sc);
  }

  // ---------------- stage B: S^T = k · q^T in ct-PAIRS; softmax per pair ----------------
  // Pair granularity = ILP sweet spot: 8 independent MFMAs per group, 32-exp VALU blocks,
  // 2 interleavable reduce trees, while live sacc stays 32 f32 (not 64) -> reg peak in stage A.
  {
    bf16x8 ka[4], qb2[4];
    #pragma unroll
    for (int rt = 0; rt < 4; rt++) ka[rt]  = ld8(&hb[KOFFS + (rt*16 + ln)*QS + quad*8]);
    #pragma unroll
    for (int ct = 0; ct < 4; ct++) qb2[ct] = ld8(&hb[(ct*16 + ln)*QS + quad*8]);

    const float* cw = cmb + (((size_t)(b & 63)*4 + h)*4096) + (ln*4 + quad)*16;
    #pragma unroll
    for (int p = 0; p < 2; p++) {
      f32x4 sacc[2][4];   // [c in pair][rt]  acc-init = combined mask+rpb table (one load)
      #pragma unroll
      for (int c = 0; c < 2; c++)
        #pragma unroll
        for (int rt = 0; rt < 4; rt++)
          sacc[c][rt] = *(const f32x4*)(cw + (p*2 + c)*1024 + rt*4);
      #pragma unroll
      for (int c = 0; c < 2; c++)
        #pragma unroll
        for (int rt = 0; rt < 4; rt++)
          sacc[c][rt] = __builtin_amdgcn_mfma_f32_16x16x32_bf16(ka[rt], qb2[p*2 + c], sacc[c][rt], 0, 0, 0);
      #pragma unroll
      for (int c = 0; c < 2; c++) {
        const int ct = p*2 + c;
        float s = 0.0f;
        #pragma unroll
        for (int rt = 0; rt < 4; rt++)
          #pragma unroll
          for (int r = 0; r < 4; r++) {
            const float e = __expf(sacc[c][rt][r]);   // m>=49 rows: -1e30 -> 0
            sacc[c][rt][r] = e;
            s += e;
          }
        s += __shfl_xor(s, 16, 64);
        s += __shfl_xor(s, 32, 64);
        const float inv = 1.0f / s;
        // P[n][m] (m r-consecutive -> b64); aliases own q/k region (per-wave DS is in-order)
        #pragma unroll
        for (int rt = 0; rt < 4; rt++)
          *(unsigned long long*)&hb[(ct*16 + ln)*PS + rt*16 + quad*4] =
              pk4(sacc[c][rt][0]*inv, sacc[c][rt][1]*inv, sacc[c][rt][2]*inv, sacc[c][rt][3]*inv);
      }
    }
  }

  // ---------------- stage C: O^T = v^T · P^T (C rows=d, cols=n) ----------------
  {
    // read ALL P frags first (v^T will overwrite P rows 0..31)
    bf16x8 pb[4][2];
    #pragma unroll
    for (int ct = 0; ct < 4; ct++)
      #pragma unroll
      for (int ks = 0; ks < 2; ks++)
        pb[ct][ks] = ld8(&hb[(ct*16 + ln)*PS + ks*32 + quad*8]);
    // spill held v^T into rows 0..31 (stride VS) — after pb reads (per-wave in-order DS)
    #pragma unroll
    for (int ci = 0; ci < 2; ci++)
      #pragma unroll
      for (int rt = 0; rt < 4; rt++)
        *(unsigned long long*)&hb[(ci*16 + ln)*VS + rt*16 + quad*4] = hv[ci][rt];
    bf16x8 va[2][2];
    #pragma unroll
    for (int rt = 0; rt < 2; rt++)
      #pragma unroll
      for (int ks = 0; ks < 2; ks++)
        va[rt][ks] = ld8(&hb[(rt*16 + ln)*VS + ks*32 + quad*8]);
    f32x4 oacc[2][4];
    #pragma unroll
    for (int rt = 0; rt < 2; rt++)
      #pragma unroll
      for (int ct = 0; ct < 4; ct++) { f32x4 z = {0.f, 0.f, 0.f, 0.f}; oacc[rt][ct] = z; }
    #pragma unroll
    for (int ks = 0; ks < 2; ks++)
      #pragma unroll
      for (int rt = 0; rt < 2; rt++)
        #pragma unroll
        for (int ct = 0; ct < 4; ct++)
          oacc[rt][ct] = __builtin_amdgcn_mfma_f32_16x16x32_bf16(va[rt][ks], pb[ct][ks], oacc[rt][ct], 0, 0, 0);
    // O[n][c-in-head] (c r-consecutive -> b64) into own head's region (overwrites v^T/P; no barrier)
    #pragma unroll
    for (int rt = 0; rt < 2; rt++)
      #pragma unroll
      for (int ct = 0; ct < 4; ct++) {
        const int n = ct*16 + ln;
        if (n < 56)   // rows 56..63 would exceed what's needed; reads of them are dead
          *(unsigned long long*)&hb[n*OS + rt*16 + quad*4] =
              pk4(oacc[rt][ct][0], oacc[rt][ct][1], oacc[rt][ct][2], oacc[rt][ct][3]);
      }
  }

  __syncthreads();   // the ONLY barrier: O slices complete before cross-head reads

  // ---------------- stage D: out^T = Wproj^T · O^T; float4 global stores ----------------
  {
    bf16x8 ob[4][4];  // [ct: n-tile][ks: c-in 32-chunk] ; chunk ks lives in head-ks's region
    #pragma unroll
    for (int ct = 0; ct < 4; ct++)
      #pragma unroll
      for (int ks = 0; ks < 4; ks++)
        ob[ct][ks] = ld8(&lds[ks*HSZ + (ct*16 + ln)*OS + quad*8]);
    // rows n in 49..63 hold pad/stale-but-finite data; their outputs are discarded below
    float* obp = out + (size_t)b * (NTOK * CDIM);
    #pragma unroll
    for (int rt = 0; rt < 2; rt++) {
      bf16x8 wpa[4];
      #pragma unroll
      for (int ks = 0; ks < 4; ks++)
        wpa[ks] = *(const bf16x8*)&pwp[((((h*2 + rt)*4 + ks)*4 + quad)*16 + ln)*8];
      const int c0 = (h*2 + rt)*16 + quad*4;
      const float4 pb4 = *(const float4*)&proj_b[c0];
      f32x4 pacc[4];
      #pragma unroll
      for (int ct = 0; ct < 4; ct++) { f32x4 bi = {pb4.x, pb4.y, pb4.z, pb4.w}; pacc[ct] = bi; }
      #pragma unroll
      for (int ks = 0; ks < 4; ks++)
        #pragma unroll
        for (int ct = 0; ct < 4; ct++)
          pacc[ct] = __builtin_amdgcn_mfma_f32_16x16x32_bf16(wpa[ks], ob[ct][ks], pacc[ct], 0, 0, 0);
      #pragma unroll
      for (int ct = 0; ct < 4; ct++) {
        const int n = ct*16 + ln;
        if (n < NTOK) {
          float4 v4;
          v4.x = pacc[ct][0]; v4.y = pacc[ct][1]; v4.z = pacc[ct][2]; v4.w = pacc[ct][3];
          *(float4*)(obp + n*CDIM + c0) = v4;
        }
      }
    }
  }
}

extern "C" void kernel_launch(void* const* d_in, const int* in_sizes, int n_in,
                              void* d_out, int out_size, void* d_ws, size_t ws_size,
                              hipStream_t stream) {
  const float* x          = (const float*)d_in[0];
  const float* mask       = (const float*)d_in[1];
  const float* qkv_w      = (const float*)d_in[2];
  const float* qkv_b      = (const float*)d_in[3];
  const float* proj_w     = (const float*)d_in[4];
  const float* proj_b     = (const float*)d_in[5];
  const float* bias_table = (const float*)d_in[6];
  const int*   rel_index  = (const int*)d_in[7];
  float* out = (float*)d_out;

  char* ws = (char*)d_ws;
  float* cmb            = (float*)ws;
  unsigned short* pwqk  = (unsigned short*)(ws + (size_t)CMB_ELEMS*4);
  unsigned short* pv    = (unsigned short*)(ws + (size_t)CMB_ELEMS*4 + (size_t)PWQK_ELEMS*2);
  unsigned short* pwp   = (unsigned short*)(ws + (size_t)CMB_ELEMS*4 + (size_t)(PWQK_ELEMS + PV_ELEMS)*2);

  // blocks 0..255: cmb (one per (w,h), LDS-staged); blocks 256..511: weight frags (1 elem/thread)
  prep_kernel<<<512, 256, 0, stream>>>(
      mask, qkv_w, proj_w, bias_table, rel_index, cmb, pwqk, pv, pwp);
  win_attn_kernel<<<4096, 256, 0, stream>>>(
      x, qkv_b, proj_b, cmb, pwqk, pv, pwp, out);
}

// Round 6
// 277.918 us; speedup vs baseline: 1.0304x; 1.0304x over previous
//
#include <hip/hip_runtime.h>
#include <hip/hip_bf16.h>

#define NTOK 49
#define CDIM 128
#define SCALE 0.17677669529663687f

// packed table sizes (elements)
#define CMB_ELEMS (64*4*4*16*4*16)    // 1048576 f32 [w][h][ct][ln][quad][rt][r] = mask+rpb (+pad)
#define PWQK_ELEMS  (4*4*4*4*16*8)    // 32768 bf16  [h][rt][ks][quad][ln][j]  (A-frags of Wq/Wk^T)
#define PV_ELEMS    (8*4*4*16*8)      // 16384 bf16  [c2][ks][quad][ln][j]     (B-frags of Wv)
#define PWP_ELEMS   (8*4*4*16*8)      // 16384 bf16  [rt][ks][quad][ln][j]     (A-frags of Wproj^T)

// LDS layout (units: shorts), per head region HSZ = 4608:
//   q[n 0..63][d stride QS=36] @0 ; k @KOFFS=2304 ; P[n][m stride PS=68] aliases q+k (4352<=4608)
//   v^T[d 0..31][m stride VS=68] written into rows 0..31 AFTER all P reads (v held in regs until then)
//   O-slice[n<56][c-in-head stride OS=36] overwrites v^T/P after their reads
// All per-wave aliasing relies on in-order DS within a wave (no barriers needed).
// Strides 36/68 (stride/2 ≡ 2 mod 4): measured 0 bank conflicts on this pattern.
//
// History:
//   r1: 2 blocks/CU (21% occ), 144 us      r2: (256,4) -> spills -> 185 us
//   r3: per-ct softmax, 3 blocks (31%), 158 us (ILP loss)
//   r4: ct-pair softmax + pre-summed mask+rpb table: 141 us; occupancy 21->30% bought only 2%
//   r5: prep rewrite (LDS-staged): total UNCHANGED -> the ~144 us remainder of dur_us is fixed
//       harness overhead; win_attn is the only lever.  Blocks run lockstep -> phase bursts;
//       more waves don't overlap (all in same phase).  => recover INTRA-wave cross-phase ILP.
//   r6 (this): stage B fully batched (32 MFMAs -> 64 indep exps -> 4 interleaved reduce trees;
//       sacc[4][4]=64 f32 fits: stage-B live ~136 < 170 budget, stage-A peak unchanged);
//       cmb loads issued before the q/k LDS round-trip; stage-D weights hoisted above barrier.
#define QS 36
#define PS 68
#define VS 68
#define OS 36
#define KOFFS (64*QS)          // 2304
#define HSZ   (2*KOFFS)        // 4608
#define LDS_SH (4*HSZ)         // 18432 shorts = 36864 B; 3 blocks -> 110 KB <= 160 KB

typedef __attribute__((ext_vector_type(8))) __bf16 bf16x8;
typedef __attribute__((ext_vector_type(4))) float f32x4;

__device__ __forceinline__ unsigned short f2bf(float f) {
  unsigned int u = __float_as_uint(f);
  u += 0x7fffu + ((u >> 16) & 1u);   // RTNE
  return (unsigned short)(u >> 16);
}

__device__ __forceinline__ unsigned int pk2(float a, float b) {
  union { __hip_bfloat162 h2; unsigned int u; } r;
  r.h2 = __float22bfloat162_rn(make_float2(a, b));
  return r.u;
}
__device__ __forceinline__ unsigned long long pk4(float a, float b, float c, float d) {
  return (unsigned long long)pk2(a, b) | ((unsigned long long)pk2(c, d) << 32);
}
__device__ __forceinline__ bf16x8 pack8(float4 a, float4 b) {
  union { bf16x8 v; unsigned int u[4]; } r;
  r.u[0] = pk2(a.x, a.y); r.u[1] = pk2(a.z, a.w);
  r.u[2] = pk2(b.x, b.y); r.u[3] = pk2(b.z, b.w);
  return r.v;
}
// two ds_read_b64 (rows are 8B- but not 16B-aligned)
__device__ __forceinline__ bf16x8 ld8(const unsigned short* p) {
  union { bf16x8 v; unsigned long long q[2]; } r;
  r.q[0] = *(const unsigned long long*)(p);
  r.q[1] = *(const unsigned long long*)(p + 4);
  return r.v;
}

// ---- prep: LDS-staged cmb build (blocks 0..255) + weight fragments (blocks 256..511) ----
__global__ __launch_bounds__(256) void prep_kernel(
    const float* __restrict__ mask,
    const float* __restrict__ qkv_w,
    const float* __restrict__ proj_w,
    const float* __restrict__ bias_table,
    const int* __restrict__ rel_index,
    float* __restrict__ cmb,
    unsigned short* __restrict__ pwqk,
    unsigned short* __restrict__ pv,
    unsigned short* __restrict__ pwp) {
  const int t = threadIdx.x;
  if (blockIdx.x < 256) {
    __shared__ float sm[NTOK * NTOK];
    __shared__ int   sri[NTOK * NTOK];
    __shared__ float sbt[169 * 4];
    const int w = blockIdx.x >> 2;
    const int h = blockIdx.x & 3;
    const float* mw = mask + (size_t)w * (NTOK * NTOK);
    for (int i = t; i < NTOK * NTOK; i += 256) { sm[i] = mw[i]; sri[i] = rel_index[i]; }
    for (int i = t; i < 169 * 4; i += 256) sbt[i] = bias_table[i];
    __syncthreads();
    float* cw = cmb + ((size_t)w * 4 + h) * 4096;
    #pragma unroll
    for (int o0 = 0; o0 < 4096; o0 += 256) {
      const int o = o0 + t;
      const int r = o & 3, rt = (o >> 2) & 3, quad = (o >> 4) & 3,
                ln = (o >> 6) & 15, ct = (o >> 10) & 3;
      const int n = ct * 16 + ln;
      const int m = rt * 16 + quad * 4 + r;
      float v;
      if (m >= NTOK)      v = -1e30f;   // masked rows: exp -> 0
      else if (n >= NTOK) v = 0.0f;     // pad cols: outputs discarded later
      else {
        const int idx = n * NTOK + m;
        v = sm[idx] + sbt[sri[idx] * 4 + h];
      }
      cw[o] = v;
    }
    return;
  }
  int i = (blockIdx.x - 256) * 256 + t;
  if (i < PWQK_ELEMS) {
    int j = i & 7, ln = (i >> 3) & 15, quad = (i >> 7) & 3, ks = (i >> 9) & 3,
        rt = (i >> 11) & 3, h = (i >> 13) & 3;
    int kk  = ks * 32 + quad * 8 + j;
    int col = (rt < 2) ? (h * 32 + rt * 16 + ln) : (128 + h * 32 + (rt - 2) * 16 + ln);
    pwqk[i] = f2bf(qkv_w[kk * 384 + col]);
    return;
  }
  i -= PWQK_ELEMS;
  if (i < PV_ELEMS) {
    int j = i & 7, ln = (i >> 3) & 15, quad = (i >> 7) & 3, ks = (i >> 9) & 3, c2 = (i >> 11) & 7;
    pv[i] = f2bf(qkv_w[(ks * 32 + quad * 8 + j) * 384 + 256 + c2 * 16 + ln]);
    return;
  }
  i -= PV_ELEMS;
  if (i < PWP_ELEMS) {
    int j = i & 7, ln = (i >> 3) & 15, quad = (i >> 7) & 3, ks = (i >> 9) & 3, rt = (i >> 11) & 7;
    pwp[i] = f2bf(proj_w[(ks * 32 + quad * 8 + j) * 128 + rt * 16 + ln]);
  }
}

// ---- fused window attention: 1 block = 1 window, wave h owns head h; ONE barrier total ----
__global__ __launch_bounds__(256, 3) void win_attn_kernel(
    const float* __restrict__ x,
    const float* __restrict__ qkv_b,
    const float* __restrict__ proj_b,
    const float* __restrict__ cmb,
    const unsigned short* __restrict__ pwqk,
    const unsigned short* __restrict__ pv,
    const unsigned short* __restrict__ pwp,
    float* __restrict__ out)
{
  __shared__ alignas(16) unsigned short lds[LDS_SH];

  const int b    = blockIdx.x;
  const int tid  = threadIdx.x;
  const int h    = tid >> 6;
  const int lane = tid & 63;
  const int ln   = lane & 15;
  const int quad = lane >> 4;

  unsigned short* hb = lds + h * HSZ;

  // ---- x fragments from global: serve as A (rows=tokens) for v-GEMM and B (cols=tokens) for q/k ----
  bf16x8 afr[4][4];
  {
    const float* xb = x + (size_t)b * (NTOK * CDIM);
    #pragma unroll
    for (int rt = 0; rt < 4; rt++) {
      const int row = rt * 16 + ln;
      #pragma unroll
      for (int ks = 0; ks < 4; ks++) {
        if (row < NTOK) {
          const float* p = xb + row * CDIM + ks * 32 + quad * 8;
          afr[rt][ks] = pack8(*(const float4*)p, *(const float4*)(p + 4));
        } else {
          union { bf16x8 v; unsigned int u[4]; } z;
          z.u[0] = z.u[1] = z.u[2] = z.u[3] = 0u;
          afr[rt][ks] = z.v;   // pad tokens -> 0; downstream q/k/v pad entries = bias (finite)
        }
      }
    }
  }

  // ---------------- stage A-v: v = x @ Wv; result HELD in regs (hv), no LDS yet ----------------
  unsigned long long hv[2][4];   // [ci: d-tile][mt: m-tile] packed 4x bf16 (m = mt*16+quad*4+r)
  #pragma unroll
  for (int ci = 0; ci < 2; ci++) {
    bf16x8 bvf[4];
    #pragma unroll
    for (int ks = 0; ks < 4; ks++)
      bvf[ks] = *(const bf16x8*)&pv[((((h*2 + ci)*4 + ks)*4 + quad)*16 + ln)*8];
    const float bvb = qkv_b[256 + (h*2 + ci)*16 + ln];
    f32x4 acc[4];
    #pragma unroll
    for (int rt = 0; rt < 4; rt++) { f32x4 bi = {bvb, bvb, bvb, bvb}; acc[rt] = bi; }
    #pragma unroll
    for (int ks = 0; ks < 4; ks++)
      #pragma unroll
      for (int rt = 0; rt < 4; rt++)
        acc[rt] = __builtin_amdgcn_mfma_f32_16x16x32_bf16(afr[rt][ks], bvf[ks], acc[rt], 0, 0, 0);
    // C: row=token m (quad*4+r), col=d (ln)  -> pack v^T[d][m] quadruples, keep in regs
    #pragma unroll
    for (int rt = 0; rt < 4; rt++)
      hv[ci][rt] = pk4(acc[rt][0], acc[rt][1], acc[rt][2], acc[rt][3]);
  }

  // ---------------- stage A-qk: qkv^T = W^T @ x^T (C rows=features) ----------------
  #pragma unroll
  for (int rt = 0; rt < 4; rt++) {
    bf16x8 awf[4];
    #pragma unroll
    for (int ks = 0; ks < 4; ks++)
      awf[ks] = *(const bf16x8*)&pwqk[((((h*4 + rt)*4 + ks)*4 + quad)*16 + ln)*8];
    const int fb = (rt < 2) ? (h*32 + rt*16 + quad*4) : (128 + h*32 + (rt - 2)*16 + quad*4);
    const float4 qb4 = *(const float4*)&qkv_b[fb];
    f32x4 acc2[4];
    #pragma unroll
    for (int ct = 0; ct < 4; ct++) { f32x4 bi = {qb4.x, qb4.y, qb4.z, qb4.w}; acc2[ct] = bi; }
    #pragma unroll
    for (int ks = 0; ks < 4; ks++)
      #pragma unroll
      for (int ct = 0; ct < 4; ct++)
        acc2[ct] = __builtin_amdgcn_mfma_f32_16x16x32_bf16(awf[ks], afr[ct][ks], acc2[ct], 0, 0, 0);
    // C: row=feature (quad*4+r), col=token n (ln) -> q[n][d] / k[m][d], d r-consecutive -> b64
    const int base = (rt < 2) ? 0 : KOFFS;
    const int d0   = (rt < 2) ? (rt*16 + quad*4) : ((rt - 2)*16 + quad*4);
    const float sc = (rt < 2) ? SCALE : 1.0f;   // fold softmax scale into q
    #pragma unroll
    for (int ct = 0; ct < 4; ct++)
      *(unsigned long long*)&hb[base + (ct*16 + ln)*QS + d0] =
          pk4(acc2[ct][0]*sc, acc2[ct][1]*sc, acc2[ct][2]*sc, acc2[ct][3]*sc);
  }

  // ---------------- stage B: S^T = k · q^T, fully batched; softmax batched over 4 ct ----------------
  // 32 independent MFMAs issued together; cmb VMEM loads issued BEFORE the q/k LDS round-trip
  // so L2 latency hides under lgkmcnt; 64 independent exps + 4 interleavable reduce trees.
  // Live regs here: sacc 64 + ka/qb 32 + hv 16 ≈ 136 < 170 budget (stage-A peak unchanged).
  {
    const float* cw = cmb + (((size_t)(b & 63)*4 + h)*4096) + (ln*4 + quad)*16;
    f32x4 sacc[4][4];   // [ct][rt]  acc-init = combined mask+rpb table
    #pragma unroll
    for (int ct = 0; ct < 4; ct++)
      #pragma unroll
      for (int rt = 0; rt < 4; rt++)
        sacc[ct][rt] = *(const f32x4*)(cw + ct*1024 + rt*4);

    bf16x8 ka[4], qb2[4];
    #pragma unroll
    for (int rt = 0; rt < 4; rt++) ka[rt]  = ld8(&hb[KOFFS + (rt*16 + ln)*QS + quad*8]);
    #pragma unroll
    for (int ct = 0; ct < 4; ct++) qb2[ct] = ld8(&hb[(ct*16 + ln)*QS + quad*8]);

    #pragma unroll
    for (int ct = 0; ct < 4; ct++)
      #pragma unroll
      for (int rt = 0; rt < 4; rt++)
        sacc[ct][rt] = __builtin_amdgcn_mfma_f32_16x16x32_bf16(ka[rt], qb2[ct], sacc[ct][rt], 0, 0, 0);

    float s[4] = {0.f, 0.f, 0.f, 0.f};
    #pragma unroll
    for (int ct = 0; ct < 4; ct++)
      #pragma unroll
      for (int rt = 0; rt < 4; rt++)
        #pragma unroll
        for (int r = 0; r < 4; r++) {
          const float e = __expf(sacc[ct][rt][r]);   // m>=49 rows: -1e30 -> 0
          sacc[ct][rt][r] = e;
          s[ct] += e;
        }
    #pragma unroll
    for (int ct = 0; ct < 4; ct++) s[ct] += __shfl_xor(s[ct], 16, 64);
    #pragma unroll
    for (int ct = 0; ct < 4; ct++) s[ct] += __shfl_xor(s[ct], 32, 64);
    #pragma unroll
    for (int ct = 0; ct < 4; ct++) {
      const float inv = 1.0f / s[ct];
      // P[n][m] (m r-consecutive -> b64); aliases own q/k region (per-wave DS is in-order)
      #pragma unroll
      for (int rt = 0; rt < 4; rt++)
        *(unsigned long long*)&hb[(ct*16 + ln)*PS + rt*16 + quad*4] =
            pk4(sacc[ct][rt][0]*inv, sacc[ct][rt][1]*inv, sacc[ct][rt][2]*inv, sacc[ct][rt][3]*inv);
    }
  }

  // ---------------- stage C: O^T = v^T · P^T (C rows=d, cols=n) ----------------
  {
    // read ALL P frags first (v^T will overwrite P rows 0..31)
    bf16x8 pb[4][2];
    #pragma unroll
    for (int ct = 0; ct < 4; ct++)
      #pragma unroll
      for (int ks = 0; ks < 2; ks++)
        pb[ct][ks] = ld8(&hb[(ct*16 + ln)*PS + ks*32 + quad*8]);
    // spill held v^T into rows 0..31 (stride VS) — after pb reads (per-wave in-order DS)
    #pragma unroll
    for (int ci = 0; ci < 2; ci++)
      #pragma unroll
      for (int rt = 0; rt < 4; rt++)
        *(unsigned long long*)&hb[(ci*16 + ln)*VS + rt*16 + quad*4] = hv[ci][rt];
    bf16x8 va[2][2];
    #pragma unroll
    for (int rt = 0; rt < 2; rt++)
      #pragma unroll
      for (int ks = 0; ks < 2; ks++)
        va[rt][ks] = ld8(&hb[(rt*16 + ln)*VS + ks*32 + quad*8]);
    f32x4 oacc[2][4];
    #pragma unroll
    for (int rt = 0; rt < 2; rt++)
      #pragma unroll
      for (int ct = 0; ct < 4; ct++) { f32x4 z = {0.f, 0.f, 0.f, 0.f}; oacc[rt][ct] = z; }
    #pragma unroll
    for (int ks = 0; ks < 2; ks++)
      #pragma unroll
      for (int rt = 0; rt < 2; rt++)
        #pragma unroll
        for (int ct = 0; ct < 4; ct++)
          oacc[rt][ct] = __builtin_amdgcn_mfma_f32_16x16x32_bf16(va[rt][ks], pb[ct][ks], oacc[rt][ct], 0, 0, 0);
    // O[n][c-in-head] (c r-consecutive -> b64) into own head's region (overwrites v^T/P; no barrier)
    #pragma unroll
    for (int rt = 0; rt < 2; rt++)
      #pragma unroll
      for (int ct = 0; ct < 4; ct++) {
        const int n = ct*16 + ln;
        if (n < 56)   // rows 56..63 would exceed what's needed; reads of them are dead
          *(unsigned long long*)&hb[n*OS + rt*16 + quad*4] =
              pk4(oacc[rt][ct][0], oacc[rt][ct][1], oacc[rt][ct][2], oacc[rt][ct][3]);
      }
  }

  // hoist stage-D weight frags + biases ABOVE the barrier: their L2 latency overlaps the
  // barrier wait instead of sitting exposed after it (lockstep DS burst follows the barrier).
  bf16x8 wpa[2][4];
  float4 pb4[2];
  #pragma unroll
  for (int rt = 0; rt < 2; rt++) {
    #pragma unroll
    for (int ks = 0; ks < 4; ks++)
      wpa[rt][ks] = *(const bf16x8*)&pwp[((((h*2 + rt)*4 + ks)*4 + quad)*16 + ln)*8];
    pb4[rt] = *(const float4*)&proj_b[(h*2 + rt)*16 + quad*4];
  }

  __syncthreads();   // the ONLY barrier: O slices complete before cross-head reads

  // ---------------- stage D: out^T = Wproj^T · O^T; float4 global stores ----------------
  {
    bf16x8 ob[4][4];  // [ct: n-tile][ks: c-in 32-chunk] ; chunk ks lives in head-ks's region
    #pragma unroll
    for (int ct = 0; ct < 4; ct++)
      #pragma unroll
      for (int ks = 0; ks < 4; ks++)
        ob[ct][ks] = ld8(&lds[ks*HSZ + (ct*16 + ln)*OS + quad*8]);
    // rows n in 49..63 hold pad/stale-but-finite data; their outputs are discarded below
    float* obp = out + (size_t)b * (NTOK * CDIM);
    #pragma unroll
    for (int rt = 0; rt < 2; rt++) {
      const int c0 = (h*2 + rt)*16 + quad*4;
      f32x4 pacc[4];
      #pragma unroll
      for (int ct = 0; ct < 4; ct++) {
        f32x4 bi = {pb4[rt].x, pb4[rt].y, pb4[rt].z, pb4[rt].w};
        pacc[ct] = bi;
      }
      #pragma unroll
      for (int ks = 0; ks < 4; ks++)
        #pragma unroll
        for (int ct = 0; ct < 4; ct++)
          pacc[ct] = __builtin_amdgcn_mfma_f32_16x16x32_bf16(wpa[rt][ks], ob[ct][ks], pacc[ct], 0, 0, 0);
      #pragma unroll
      for (int ct = 0; ct < 4; ct++) {
        const int n = ct*16 + ln;
        if (n < NTOK) {
          float4 v4;
          v4.x = pacc[ct][0]; v4.y = pacc[ct][1]; v4.z = pacc[ct][2]; v4.w = pacc[ct][3];
          *(float4*)(obp + n*CDIM + c0) = v4;
        }
      }
    }
  }
}

extern "C" void kernel_launch(void* const* d_in, const int* in_sizes, int n_in,
                              void* d_out, int out_size, void* d_ws, size_t ws_size,
                              hipStream_t stream) {
  const float* x          = (const float*)d_in[0];
  const float* mask       = (const float*)d_in[1];
  const float* qkv_w      = (const float*)d_in[2];
  const float* qkv_b      = (const float*)d_in[3];
  const float* proj_w     = (const float*)d_in[4];
  const float* proj_b     = (const float*)d_in[5];
  const float* bias_table = (const float*)d_in[6];
  const int*   rel_index  = (const int*)d_in[7];
  float* out = (float*)d_out;

  char* ws = (char*)d_ws;
  float* cmb            = (float*)ws;
  unsigned short* pwqk  = (unsigned short*)(ws + (size_t)CMB_ELEMS*4);
  unsigned short* pv    = (unsigned short*)(ws + (size_t)CMB_ELEMS*4 + (size_t)PWQK_ELEMS*2);
  unsigned short* pwp   = (unsigned short*)(ws + (size_t)CMB_ELEMS*4 + (size_t)(PWQK_ELEMS + PV_ELEMS)*2);

  // blocks 0..255: cmb (one per (w,h), LDS-staged); blocks 256..511: weight frags (1 elem/thread)
  prep_kernel<<<512, 256, 0, stream>>>(
      mask, qkv_w, proj_w, bias_table, rel_index, cmb, pwqk, pv, pwp);
  win_attn_kernel<<<4096, 256, 0, stream>>>(
      x, qkv_b, proj_b, cmb, pwqk, pv, pwp, out);
}

// Round 7
// 274.977 us; speedup vs baseline: 1.0414x; 1.0107x over previous
//
#include <hip/hip_runtime.h>
#include <hip/hip_bf16.h>

#define NTOK 49
#define CDIM 128
#define SCALE 0.17677669529663687f
#define LOG2E 1.4426950408889634f

// packed table sizes (elements)
#define CMB_ELEMS (64*4*4*16*4*16)    // 1048576 f32 [w][h][ct][ln][quad][rt][r] = (mask+rpb)*LOG2E
#define PWQK_ELEMS  (4*4*4*4*16*8)    // 32768 bf16  [h][rt][ks][quad][ln][j]  (A-frags of Wq/Wk^T)
#define PV_ELEMS    (8*4*4*16*8)      // 16384 bf16  [c2][ks][quad][ln][j]     (B-frags of Wv)
#define PWP_ELEMS   (8*4*4*16*8)      // 16384 bf16  [rt][ks][quad][ln][j]     (A-frags of Wproj^T)

// LDS layout (units: shorts), per head region HSZ = 5120:
//   q[n 0..63][d stride QS=40] @0 ; k @KOFFS=2560 ; P[n][m stride PS=72] aliases q+k (4608<=5120)
//   v^T[d 0..31][m stride VS=72] written into rows 0..31 AFTER all P reads (v held in regs)
//   O-slice[n<56][c stride OS=40] overwrites v^T/P after their reads
// r7: strides padded so ALL reads are 16B-aligned -> single ds_read_b128 (was 2x ds_read_b64).
//   Read-bank pattern: 16-lane groups hit 8 distinct 4-bank spans, uniform 2-way worst case
//   (2-way measured free for b32/b64 — watch SQ_LDS_BANK_CONFLICT, currently 0, as diagnostic).
//
// History:
//   r1 144us (2 blk/CU) | r2 185us (reg-cap spills) | r3 158us (per-ct ILP loss)
//   r4 141us (ct-pair + cmb table) | r5 prep rewrite: total unchanged -> remainder is harness
//   r6 140us: batched stage B, hoists — NULL.  Cycle model: VALU ISSUE is the largest busy
//   component (~2000 insts/wave, 2cy each, wave64 on SIMD-32); occupancy+ILP nulls consistent
//   with issue-bound.  r7: cut instruction count: b128 LDS reads (QS/OS=40, PS/VS=72),
//   exp2-fold (kill 64 muls), late-normalize (store raw e, scale O by inv: -32 muls),
//   setprio around MFMA clusters.
#define QS 40
#define PS 72
#define VS 72
#define OS 40
#define KOFFS (64*QS)          // 2560
#define HSZ   (2*KOFFS)        // 5120
#define LDS_SH (4*HSZ)         // 20480 shorts = 40960 B = 80*512; 3 blocks -> 120 KB <= 160 KB

typedef __attribute__((ext_vector_type(8))) __bf16 bf16x8;
typedef __attribute__((ext_vector_type(4))) float f32x4;

__device__ __forceinline__ unsigned short f2bf(float f) {
  unsigned int u = __float_as_uint(f);
  u += 0x7fffu + ((u >> 16) & 1u);   // RTNE
  return (unsigned short)(u >> 16);
}

__device__ __forceinline__ unsigned int pk2(float a, float b) {
  union { __hip_bfloat162 h2; unsigned int u; } r;
  r.h2 = __float22bfloat162_rn(make_float2(a, b));
  return r.u;
}
__device__ __forceinline__ unsigned long long pk4(float a, float b, float c, float d) {
  return (unsigned long long)pk2(a, b) | ((unsigned long long)pk2(c, d) << 32);
}
__device__ __forceinline__ bf16x8 pack8(float4 a, float4 b) {
  union { bf16x8 v; unsigned int u[4]; } r;
  r.u[0] = pk2(a.x, a.y); r.u[1] = pk2(a.z, a.w);
  r.u[2] = pk2(b.x, b.y); r.u[3] = pk2(b.z, b.w);
  return r.v;
}
// single ds_read_b128 (all read rows are 16B-aligned with the padded strides)
__device__ __forceinline__ bf16x8 ld16(const unsigned short* p) {
  return *(const bf16x8*)__builtin_assume_aligned(p, 16);
}

// ---- prep: LDS-staged cmb build (blocks 0..255) + weight fragments (blocks 256..511) ----
__global__ __launch_bounds__(256) void prep_kernel(
    const float* __restrict__ mask,
    const float* __restrict__ qkv_w,
    const float* __restrict__ proj_w,
    const float* __restrict__ bias_table,
    const int* __restrict__ rel_index,
    float* __restrict__ cmb,
    unsigned short* __restrict__ pwqk,
    unsigned short* __restrict__ pv,
    unsigned short* __restrict__ pwp) {
  const int t = threadIdx.x;
  if (blockIdx.x < 256) {
    __shared__ float sm[NTOK * NTOK];
    __shared__ int   sri[NTOK * NTOK];
    __shared__ float sbt[169 * 4];
    const int w = blockIdx.x >> 2;
    const int h = blockIdx.x & 3;
    const float* mw = mask + (size_t)w * (NTOK * NTOK);
    for (int i = t; i < NTOK * NTOK; i += 256) { sm[i] = mw[i]; sri[i] = rel_index[i]; }
    for (int i = t; i < 169 * 4; i += 256) sbt[i] = bias_table[i];
    __syncthreads();
    float* cw = cmb + ((size_t)w * 4 + h) * 4096;
    #pragma unroll
    for (int o0 = 0; o0 < 4096; o0 += 256) {
      const int o = o0 + t;
      const int r = o & 3, rt = (o >> 2) & 3, quad = (o >> 4) & 3,
                ln = (o >> 6) & 15, ct = (o >> 10) & 3;
      const int n = ct * 16 + ln;
      const int m = rt * 16 + quad * 4 + r;
      float v;
      if (m >= NTOK)      v = -1e30f;   // masked rows: exp2 -> 0
      else if (n >= NTOK) v = 0.0f;     // pad cols: outputs discarded later
      else {
        const int idx = n * NTOK + m;
        v = (sm[idx] + sbt[sri[idx] * 4 + h]) * LOG2E;   // pre-scale for exp2
      }
      cw[o] = v;
    }
    return;
  }
  int i = (blockIdx.x - 256) * 256 + t;
  if (i < PWQK_ELEMS) {
    int j = i & 7, ln = (i >> 3) & 15, quad = (i >> 7) & 3, ks = (i >> 9) & 3,
        rt = (i >> 11) & 3, h = (i >> 13) & 3;
    int kk  = ks * 32 + quad * 8 + j;
    int col = (rt < 2) ? (h * 32 + rt * 16 + ln) : (128 + h * 32 + (rt - 2) * 16 + ln);
    pwqk[i] = f2bf(qkv_w[kk * 384 + col]);
    return;
  }
  i -= PWQK_ELEMS;
  if (i < PV_ELEMS) {
    int j = i & 7, ln = (i >> 3) & 15, quad = (i >> 7) & 3, ks = (i >> 9) & 3, c2 = (i >> 11) & 7;
    pv[i] = f2bf(qkv_w[(ks * 32 + quad * 8 + j) * 384 + 256 + c2 * 16 + ln]);
    return;
  }
  i -= PV_ELEMS;
  if (i < PWP_ELEMS) {
    int j = i & 7, ln = (i >> 3) & 15, quad = (i >> 7) & 3, ks = (i >> 9) & 3, rt = (i >> 11) & 7;
    pwp[i] = f2bf(proj_w[(ks * 32 + quad * 8 + j) * 128 + rt * 16 + ln]);
  }
}

// ---- fused window attention: 1 block = 1 window, wave h owns head h; ONE barrier total ----
__global__ __launch_bounds__(256, 3) void win_attn_kernel(
    const float* __restrict__ x,
    const float* __restrict__ qkv_b,
    const float* __restrict__ proj_b,
    const float* __restrict__ cmb,
    const unsigned short* __restrict__ pwqk,
    const unsigned short* __restrict__ pv,
    const unsigned short* __restrict__ pwp,
    float* __restrict__ out)
{
  __shared__ alignas(16) unsigned short lds[LDS_SH];

  const int b    = blockIdx.x;
  const int tid  = threadIdx.x;
  const int h    = tid >> 6;
  const int lane = tid & 63;
  const int ln   = lane & 15;
  const int quad = lane >> 4;

  unsigned short* hb = lds + h * HSZ;

  // ---- x fragments from global: serve as A (rows=tokens) for v-GEMM and B (cols=tokens) for q/k ----
  bf16x8 afr[4][4];
  {
    const float* xb = x + (size_t)b * (NTOK * CDIM);
    #pragma unroll
    for (int rt = 0; rt < 4; rt++) {
      const int row = rt * 16 + ln;
      #pragma unroll
      for (int ks = 0; ks < 4; ks++) {
        if (row < NTOK) {
          const float* p = xb + row * CDIM + ks * 32 + quad * 8;
          afr[rt][ks] = pack8(*(const float4*)p, *(const float4*)(p + 4));
        } else {
          union { bf16x8 v; unsigned int u[4]; } z;
          z.u[0] = z.u[1] = z.u[2] = z.u[3] = 0u;
          afr[rt][ks] = z.v;   // pad tokens -> 0; downstream q/k/v pad entries = bias (finite)
        }
      }
    }
  }

  // ---------------- stage A-v: v = x @ Wv; result HELD in regs (hv), no LDS yet ----------------
  unsigned long long hv[2][4];   // [ci: d-tile][mt: m-tile] packed 4x bf16 (m = mt*16+quad*4+r)
  #pragma unroll
  for (int ci = 0; ci < 2; ci++) {
    bf16x8 bvf[4];
    #pragma unroll
    for (int ks = 0; ks < 4; ks++)
      bvf[ks] = *(const bf16x8*)&pv[((((h*2 + ci)*4 + ks)*4 + quad)*16 + ln)*8];
    const float bvb = qkv_b[256 + (h*2 + ci)*16 + ln];
    f32x4 acc[4];
    #pragma unroll
    for (int rt = 0; rt < 4; rt++) { f32x4 bi = {bvb, bvb, bvb, bvb}; acc[rt] = bi; }
    __builtin_amdgcn_s_setprio(1);
    #pragma unroll
    for (int ks = 0; ks < 4; ks++)
      #pragma unroll
      for (int rt = 0; rt < 4; rt++)
        acc[rt] = __builtin_amdgcn_mfma_f32_16x16x32_bf16(afr[rt][ks], bvf[ks], acc[rt], 0, 0, 0);
    __builtin_amdgcn_s_setprio(0);
    // C: row=token m (quad*4+r), col=d (ln)  -> pack v^T[d][m] quadruples, keep in regs
    #pragma unroll
    for (int rt = 0; rt < 4; rt++)
      hv[ci][rt] = pk4(acc[rt][0], acc[rt][1], acc[rt][2], acc[rt][3]);
  }

  // ---------------- stage A-qk: qkv^T = W^T @ x^T (C rows=features) ----------------
  #pragma unroll
  for (int rt = 0; rt < 4; rt++) {
    bf16x8 awf[4];
    #pragma unroll
    for (int ks = 0; ks < 4; ks++)
      awf[ks] = *(const bf16x8*)&pwqk[((((h*4 + rt)*4 + ks)*4 + quad)*16 + ln)*8];
    const int fb = (rt < 2) ? (h*32 + rt*16 + quad*4) : (128 + h*32 + (rt - 2)*16 + quad*4);
    const float4 qb4 = *(const float4*)&qkv_b[fb];
    f32x4 acc2[4];
    #pragma unroll
    for (int ct = 0; ct < 4; ct++) { f32x4 bi = {qb4.x, qb4.y, qb4.z, qb4.w}; acc2[ct] = bi; }
    __builtin_amdgcn_s_setprio(1);
    #pragma unroll
    for (int ks = 0; ks < 4; ks++)
      #pragma unroll
      for (int ct = 0; ct < 4; ct++)
        acc2[ct] = __builtin_amdgcn_mfma_f32_16x16x32_bf16(awf[ks], afr[ct][ks], acc2[ct], 0, 0, 0);
    __builtin_amdgcn_s_setprio(0);
    // C: row=feature (quad*4+r), col=token n (ln) -> q[n][d] / k[m][d], d r-consecutive -> b64
    const int base = (rt < 2) ? 0 : KOFFS;
    const int d0   = (rt < 2) ? (rt*16 + quad*4) : ((rt - 2)*16 + quad*4);
    const float sc = (rt < 2) ? (SCALE * LOG2E) : 1.0f;   // fold softmax scale AND log2e into q
    #pragma unroll
    for (int ct = 0; ct < 4; ct++)
      *(unsigned long long*)&hb[base + (ct*16 + ln)*QS + d0] =
          pk4(acc2[ct][0]*sc, acc2[ct][1]*sc, acc2[ct][2]*sc, acc2[ct][3]*sc);
  }

  // ---------------- stage B: S^T = k · q^T, fully batched; softmax batched over 4 ct ----------------
  // exp2 on pre-scaled logits (v_exp_f32 is 2^x natively); P stored UNNORMALIZED (e <= ~e^1,
  // bf16-safe: logits are small + mask in {0,-100}); inv[] passed to stage C for late normalize.
  float inv[4];
  {
    const float* cw = cmb + (((size_t)(b & 63)*4 + h)*4096) + (ln*4 + quad)*16;
    f32x4 sacc[4][4];   // [ct][rt]  acc-init = combined (mask+rpb)*LOG2E table
    #pragma unroll
    for (int ct = 0; ct < 4; ct++)
      #pragma unroll
      for (int rt = 0; rt < 4; rt++)
        sacc[ct][rt] = *(const f32x4*)(cw + ct*1024 + rt*4);

    bf16x8 ka[4], qb2[4];
    #pragma unroll
    for (int rt = 0; rt < 4; rt++) ka[rt]  = ld16(&hb[KOFFS + (rt*16 + ln)*QS + quad*8]);
    #pragma unroll
    for (int ct = 0; ct < 4; ct++) qb2[ct] = ld16(&hb[(ct*16 + ln)*QS + quad*8]);

    __builtin_amdgcn_s_setprio(1);
    #pragma unroll
    for (int ct = 0; ct < 4; ct++)
      #pragma unroll
      for (int rt = 0; rt < 4; rt++)
        sacc[ct][rt] = __builtin_amdgcn_mfma_f32_16x16x32_bf16(ka[rt], qb2[ct], sacc[ct][rt], 0, 0, 0);
    __builtin_amdgcn_s_setprio(0);

    float s[4] = {0.f, 0.f, 0.f, 0.f};
    #pragma unroll
    for (int ct = 0; ct < 4; ct++)
      #pragma unroll
      for (int rt = 0; rt < 4; rt++)
        #pragma unroll
        for (int r = 0; r < 4; r++) {
          const float e = __builtin_amdgcn_exp2f(sacc[ct][rt][r]);   // m>=49 rows: -1e30 -> 0
          sacc[ct][rt][r] = e;
          s[ct] += e;
        }
    #pragma unroll
    for (int ct = 0; ct < 4; ct++) s[ct] += __shfl_xor(s[ct], 16, 64);
    #pragma unroll
    for (int ct = 0; ct < 4; ct++) s[ct] += __shfl_xor(s[ct], 32, 64);
    #pragma unroll
    for (int ct = 0; ct < 4; ct++) inv[ct] = 1.0f / s[ct];
    // P[n][m] raw e values (m r-consecutive -> b64); aliases own q/k region (per-wave in-order DS)
    #pragma unroll
    for (int ct = 0; ct < 4; ct++)
      #pragma unroll
      for (int rt = 0; rt < 4; rt++)
        *(unsigned long long*)&hb[(ct*16 + ln)*PS + rt*16 + quad*4] =
            pk4(sacc[ct][rt][0], sacc[ct][rt][1], sacc[ct][rt][2], sacc[ct][rt][3]);
  }

  // ---------------- stage C: O^T = v^T · E^T, then scale cols by inv (late normalize) ----------------
  {
    // read ALL P frags first (v^T will overwrite P rows 0..31)
    bf16x8 pb[4][2];
    #pragma unroll
    for (int ct = 0; ct < 4; ct++)
      #pragma unroll
      for (int ks = 0; ks < 2; ks++)
        pb[ct][ks] = ld16(&hb[(ct*16 + ln)*PS + ks*32 + quad*8]);
    // spill held v^T into rows 0..31 (stride VS) — after pb reads (per-wave in-order DS)
    #pragma unroll
    for (int ci = 0; ci < 2; ci++)
      #pragma unroll
      for (int rt = 0; rt < 4; rt++)
        *(unsigned long long*)&hb[(ci*16 + ln)*VS + rt*16 + quad*4] = hv[ci][rt];
    bf16x8 va[2][2];
    #pragma unroll
    for (int rt = 0; rt < 2; rt++)
      #pragma unroll
      for (int ks = 0; ks < 2; ks++)
        va[rt][ks] = ld16(&hb[(rt*16 + ln)*VS + ks*32 + quad*8]);
    f32x4 oacc[2][4];
    #pragma unroll
    for (int rt = 0; rt < 2; rt++)
      #pragma unroll
      for (int ct = 0; ct < 4; ct++) { f32x4 z = {0.f, 0.f, 0.f, 0.f}; oacc[rt][ct] = z; }
    __builtin_amdgcn_s_setprio(1);
    #pragma unroll
    for (int ks = 0; ks < 2; ks++)
      #pragma unroll
      for (int rt = 0; rt < 2; rt++)
        #pragma unroll
        for (int ct = 0; ct < 4; ct++)
          oacc[rt][ct] = __builtin_amdgcn_mfma_f32_16x16x32_bf16(va[rt][ks], pb[ct][ks], oacc[rt][ct], 0, 0, 0);
    __builtin_amdgcn_s_setprio(0);
    // C cols n = ct*16+ln: SAME lane mapping as stage-B's s[ct] -> scale by inv[ct] here.
    // O[n][c-in-head] (c r-consecutive -> b64) into own head's region (overwrites v^T/P; no barrier)
    #pragma unroll
    for (int rt = 0; rt < 2; rt++)
      #pragma unroll
      for (int ct = 0; ct < 4; ct++) {
        const int n = ct*16 + ln;
        if (n < 56)   // rows 56..63 would exceed what's needed; reads of them are dead
          *(unsigned long long*)&hb[n*OS + rt*16 + quad*4] =
              pk4(oacc[rt][ct][0]*inv[ct], oacc[rt][ct][1]*inv[ct],
                  oacc[rt][ct][2]*inv[ct], oacc[rt][ct][3]*inv[ct]);
      }
  }

  // hoist stage-D weight frags + biases ABOVE the barrier: their L2 latency overlaps the
  // barrier wait instead of sitting exposed after it.
  bf16x8 wpa[2][4];
  float4 pb4[2];
  #pragma unroll
  for (int rt = 0; rt < 2; rt++) {
    #pragma unroll
    for (int ks = 0; ks < 4; ks++)
      wpa[rt][ks] = *(const bf16x8*)&pwp[((((h*2 + rt)*4 + ks)*4 + quad)*16 + ln)*8];
    pb4[rt] = *(const float4*)&proj_b[(h*2 + rt)*16 + quad*4];
  }

  __syncthreads();   // the ONLY barrier: O slices complete before cross-head reads

  // ---------------- stage D: out^T = Wproj^T · O^T; float4 global stores ----------------
  {
    bf16x8 ob[4][4];  // [ct: n-tile][ks: c-in 32-chunk] ; chunk ks lives in head-ks's region
    #pragma unroll
    for (int ct = 0; ct < 4; ct++)
      #pragma unroll
      for (int ks = 0; ks < 4; ks++)
        ob[ct][ks] = ld16(&lds[ks*HSZ + (ct*16 + ln)*OS + quad*8]);
    // rows n in 49..63 hold pad/stale-but-finite data; their outputs are discarded below
    float* obp = out + (size_t)b * (NTOK * CDIM);
    #pragma unroll
    for (int rt = 0; rt < 2; rt++) {
      const int c0 = (h*2 + rt)*16 + quad*4;
      f32x4 pacc[4];
      #pragma unroll
      for (int ct = 0; ct < 4; ct++) {
        f32x4 bi = {pb4[rt].x, pb4[rt].y, pb4[rt].z, pb4[rt].w};
        pacc[ct] = bi;
      }
      __builtin_amdgcn_s_setprio(1);
      #pragma unroll
      for (int ks = 0; ks < 4; ks++)
        #pragma unroll
        for (int ct = 0; ct < 4; ct++)
          pacc[ct] = __builtin_amdgcn_mfma_f32_16x16x32_bf16(wpa[rt][ks], ob[ct][ks], pacc[ct], 0, 0, 0);
      __builtin_amdgcn_s_setprio(0);
      #pragma unroll
      for (int ct = 0; ct < 4; ct++) {
        const int n = ct*16 + ln;
        if (n < NTOK) {
          float4 v4;
          v4.x = pacc[ct][0]; v4.y = pacc[ct][1]; v4.z = pacc[ct][2]; v4.w = pacc[ct][3];
          *(float4*)(obp + n*CDIM + c0) = v4;
        }
      }
    }
  }
}

extern "C" void kernel_launch(void* const* d_in, const int* in_sizes, int n_in,
                              void* d_out, int out_size, void* d_ws, size_t ws_size,
                              hipStream_t stream) {
  const float* x          = (const float*)d_in[0];
  const float* mask       = (const float*)d_in[1];
  const float* qkv_w      = (const float*)d_in[2];
  const float* qkv_b      = (const float*)d_in[3];
  const float* proj_w     = (const float*)d_in[4];
  const float* proj_b     = (const float*)d_in[5];
  const float* bias_table = (const float*)d_in[6];
  const int*   rel_index  = (const int*)d_in[7];
  float* out = (float*)d_out;

  char* ws = (char*)d_ws;
  float* cmb            = (float*)ws;
  unsigned short* pwqk  = (unsigned short*)(ws + (size_t)CMB_ELEMS*4);
  unsigned short* pv    = (unsigned short*)(ws + (size_t)CMB_ELEMS*4 + (size_t)PWQK_ELEMS*2);
  unsigned short* pwp   = (unsigned short*)(ws + (size_t)CMB_ELEMS*4 + (size_t)(PWQK_ELEMS + PV_ELEMS)*2);

  // blocks 0..255: cmb (one per (w,h), LDS-staged); blocks 256..511: weight frags (1 elem/thread)
  prep_kernel<<<512, 256, 0, stream>>>(
      mask, qkv_w, proj_w, bias_table, rel_index, cmb, pwqk, pv, pwp);
  win_attn_kernel<<<4096, 256, 0, stream>>>(
      x, qkv_b, proj_b, cmb, pwqk, pv, pwp, out);
}

// Round 8
// 274.585 us; speedup vs baseline: 1.0429x; 1.0014x over previous
//
#include <hip/hip_runtime.h>
#include <hip/hip_bf16.h>

#define NTOK 49
#define CDIM 128
#define SCALE 0.17677669529663687f
#define LOG2E 1.4426950408889634f

// packed table sizes (elements)
#define CMB_ELEMS (64*4*4*16*4*16)    // 1048576 f32 [w][h][ct][ln][quad][rt][r] = (mask+rpb)*LOG2E
#define PWQK_ELEMS  (4*4*4*4*16*8)    // 32768 bf16  [h][rt][ks][quad][ln][j]  (A-frags of Wq/Wk^T)
#define PV_ELEMS    (8*4*4*16*8)      // 16384 bf16  [c2][ks][quad][ln][j]     (B-frags of Wv)
#define PWP_ELEMS   (8*4*4*16*8)      // 16384 bf16  [rt][ks][quad][ln][j]     (A-frags of Wproj^T)

// LDS layout (units: shorts), per head region HSZ = 4608  (r6 geometry RESTORED):
//   q[n 0..63][d stride QS=36] @0 ; k @KOFFS=2304 ; P[n][m stride PS=68] aliases q+k (4352<=4608)
//   v^T[d 0..31][m stride VS=68] written into rows 0..31 AFTER all P reads (v held in regs)
//   O-slice[n<56][c stride OS=36] overwrites v^T/P after their reads
// Strides 36/68 shorts = 18/34 dwords: ln*18 mod 32 and ln*34 mod 32 each hit 16 DISTINCT even
// residues -> b64 extents tile all 32 banks exactly -> measured 0 bank conflicts.
// r7 LESSON: padding strides to 16B (20/36 dwords) for ds_read_b128 collapsed this to 8 residues
// (lanes ln, ln+8 collide) -> 5.37M conflict cycles = +8.7us > the 3.6us VALU win.  b128 requires
// 16B alignment, incompatible with odd-dword-pair strides; b64 reads + clean banks win.
//
// History: r1 144 | r2 185 (spills) | r3 158 (ILP loss) | r4 141 | r5 prep null (harness floor)
//   r6 140 (batched B, hoists) | r7 148.5: -3.6us VALU (exp2/late-norm GOOD) +8.7us conflicts (b128 BAD)
//   r8 (this): r6 geometry + exp2-fold + late-normalize + setprio, no b128.
#define QS 36
#define PS 68
#define VS 68
#define OS 36
#define KOFFS (64*QS)          // 2304
#define HSZ   (2*KOFFS)        // 4608
#define LDS_SH (4*HSZ)         // 18432 shorts = 36864 B; 3 blocks -> 110 KB <= 160 KB

typedef __attribute__((ext_vector_type(8))) __bf16 bf16x8;
typedef __attribute__((ext_vector_type(4))) float f32x4;

__device__ __forceinline__ unsigned short f2bf(float f) {
  unsigned int u = __float_as_uint(f);
  u += 0x7fffu + ((u >> 16) & 1u);   // RTNE
  return (unsigned short)(u >> 16);
}

__device__ __forceinline__ unsigned int pk2(float a, float b) {
  union { __hip_bfloat162 h2; unsigned int u; } r;
  r.h2 = __float22bfloat162_rn(make_float2(a, b));
  return r.u;
}
__device__ __forceinline__ unsigned long long pk4(float a, float b, float c, float d) {
  return (unsigned long long)pk2(a, b) | ((unsigned long long)pk2(c, d) << 32);
}
__device__ __forceinline__ bf16x8 pack8(float4 a, float4 b) {
  union { bf16x8 v; unsigned int u[4]; } r;
  r.u[0] = pk2(a.x, a.y); r.u[1] = pk2(a.z, a.w);
  r.u[2] = pk2(b.x, b.y); r.u[3] = pk2(b.z, b.w);
  return r.v;
}
// two ds_read_b64 (rows are 8B- but not 16B-aligned; conflict-free on 18/34-dword strides)
__device__ __forceinline__ bf16x8 ld8(const unsigned short* p) {
  union { bf16x8 v; unsigned long long q[2]; } r;
  r.q[0] = *(const unsigned long long*)(p);
  r.q[1] = *(const unsigned long long*)(p + 4);
  return r.v;
}

// ---- prep: LDS-staged cmb build (blocks 0..255) + weight fragments (blocks 256..511) ----
__global__ __launch_bounds__(256) void prep_kernel(
    const float* __restrict__ mask,
    const float* __restrict__ qkv_w,
    const float* __restrict__ proj_w,
    const float* __restrict__ bias_table,
    const int* __restrict__ rel_index,
    float* __restrict__ cmb,
    unsigned short* __restrict__ pwqk,
    unsigned short* __restrict__ pv,
    unsigned short* __restrict__ pwp) {
  const int t = threadIdx.x;
  if (blockIdx.x < 256) {
    __shared__ float sm[NTOK * NTOK];
    __shared__ int   sri[NTOK * NTOK];
    __shared__ float sbt[169 * 4];
    const int w = blockIdx.x >> 2;
    const int h = blockIdx.x & 3;
    const float* mw = mask + (size_t)w * (NTOK * NTOK);
    for (int i = t; i < NTOK * NTOK; i += 256) { sm[i] = mw[i]; sri[i] = rel_index[i]; }
    for (int i = t; i < 169 * 4; i += 256) sbt[i] = bias_table[i];
    __syncthreads();
    float* cw = cmb + ((size_t)w * 4 + h) * 4096;
    #pragma unroll
    for (int o0 = 0; o0 < 4096; o0 += 256) {
      const int o = o0 + t;
      const int r = o & 3, rt = (o >> 2) & 3, quad = (o >> 4) & 3,
                ln = (o >> 6) & 15, ct = (o >> 10) & 3;
      const int n = ct * 16 + ln;
      const int m = rt * 16 + quad * 4 + r;
      float v;
      if (m >= NTOK)      v = -1e30f;   // masked rows: exp2 -> 0
      else if (n >= NTOK) v = 0.0f;     // pad cols: outputs discarded later
      else {
        const int idx = n * NTOK + m;
        v = (sm[idx] + sbt[sri[idx] * 4 + h]) * LOG2E;   // pre-scale for exp2
      }
      cw[o] = v;
    }
    return;
  }
  int i = (blockIdx.x - 256) * 256 + t;
  if (i < PWQK_ELEMS) {
    int j = i & 7, ln = (i >> 3) & 15, quad = (i >> 7) & 3, ks = (i >> 9) & 3,
        rt = (i >> 11) & 3, h = (i >> 13) & 3;
    int kk  = ks * 32 + quad * 8 + j;
    int col = (rt < 2) ? (h * 32 + rt * 16 + ln) : (128 + h * 32 + (rt - 2) * 16 + ln);
    pwqk[i] = f2bf(qkv_w[kk * 384 + col]);
    return;
  }
  i -= PWQK_ELEMS;
  if (i < PV_ELEMS) {
    int j = i & 7, ln = (i >> 3) & 15, quad = (i >> 7) & 3, ks = (i >> 9) & 3, c2 = (i >> 11) & 7;
    pv[i] = f2bf(qkv_w[(ks * 32 + quad * 8 + j) * 384 + 256 + c2 * 16 + ln]);
    return;
  }
  i -= PV_ELEMS;
  if (i < PWP_ELEMS) {
    int j = i & 7, ln = (i >> 3) & 15, quad = (i >> 7) & 3, ks = (i >> 9) & 3, rt = (i >> 11) & 7;
    pwp[i] = f2bf(proj_w[(ks * 32 + quad * 8 + j) * 128 + rt * 16 + ln]);
  }
}

// ---- fused window attention: 1 block = 1 window, wave h owns head h; ONE barrier total ----
__global__ __launch_bounds__(256, 3) void win_attn_kernel(
    const float* __restrict__ x,
    const float* __restrict__ qkv_b,
    const float* __restrict__ proj_b,
    const float* __restrict__ cmb,
    const unsigned short* __restrict__ pwqk,
    const unsigned short* __restrict__ pv,
    const unsigned short* __restrict__ pwp,
    float* __restrict__ out)
{
  __shared__ alignas(16) unsigned short lds[LDS_SH];

  const int b    = blockIdx.x;
  const int tid  = threadIdx.x;
  const int h    = tid >> 6;
  const int lane = tid & 63;
  const int ln   = lane & 15;
  const int quad = lane >> 4;

  unsigned short* hb = lds + h * HSZ;

  // ---- x fragments from global: serve as A (rows=tokens) for v-GEMM and B (cols=tokens) for q/k ----
  bf16x8 afr[4][4];
  {
    const float* xb = x + (size_t)b * (NTOK * CDIM);
    #pragma unroll
    for (int rt = 0; rt < 4; rt++) {
      const int row = rt * 16 + ln;
      #pragma unroll
      for (int ks = 0; ks < 4; ks++) {
        if (row < NTOK) {
          const float* p = xb + row * CDIM + ks * 32 + quad * 8;
          afr[rt][ks] = pack8(*(const float4*)p, *(const float4*)(p + 4));
        } else {
          union { bf16x8 v; unsigned int u[4]; } z;
          z.u[0] = z.u[1] = z.u[2] = z.u[3] = 0u;
          afr[rt][ks] = z.v;   // pad tokens -> 0; downstream q/k/v pad entries = bias (finite)
        }
      }
    }
  }

  // ---------------- stage A-v: v = x @ Wv; result HELD in regs (hv), no LDS yet ----------------
  unsigned long long hv[2][4];   // [ci: d-tile][mt: m-tile] packed 4x bf16 (m = mt*16+quad*4+r)
  #pragma unroll
  for (int ci = 0; ci < 2; ci++) {
    bf16x8 bvf[4];
    #pragma unroll
    for (int ks = 0; ks < 4; ks++)
      bvf[ks] = *(const bf16x8*)&pv[((((h*2 + ci)*4 + ks)*4 + quad)*16 + ln)*8];
    const float bvb = qkv_b[256 + (h*2 + ci)*16 + ln];
    f32x4 acc[4];
    #pragma unroll
    for (int rt = 0; rt < 4; rt++) { f32x4 bi = {bvb, bvb, bvb, bvb}; acc[rt] = bi; }
    __builtin_amdgcn_s_setprio(1);
    #pragma unroll
    for (int ks = 0; ks < 4; ks++)
      #pragma unroll
      for (int rt = 0; rt < 4; rt++)
        acc[rt] = __builtin_amdgcn_mfma_f32_16x16x32_bf16(afr[rt][ks], bvf[ks], acc[rt], 0, 0, 0);
    __builtin_amdgcn_s_setprio(0);
    // C: row=token m (quad*4+r), col=d (ln)  -> pack v^T[d][m] quadruples, keep in regs
    #pragma unroll
    for (int rt = 0; rt < 4; rt++)
      hv[ci][rt] = pk4(acc[rt][0], acc[rt][1], acc[rt][2], acc[rt][3]);
  }

  // ---------------- stage A-qk: qkv^T = W^T @ x^T (C rows=features) ----------------
  #pragma unroll
  for (int rt = 0; rt < 4; rt++) {
    bf16x8 awf[4];
    #pragma unroll
    for (int ks = 0; ks < 4; ks++)
      awf[ks] = *(const bf16x8*)&pwqk[((((h*4 + rt)*4 + ks)*4 + quad)*16 + ln)*8];
    const int fb = (rt < 2) ? (h*32 + rt*16 + quad*4) : (128 + h*32 + (rt - 2)*16 + quad*4);
    const float4 qb4 = *(const float4*)&qkv_b[fb];
    f32x4 acc2[4];
    #pragma unroll
    for (int ct = 0; ct < 4; ct++) { f32x4 bi = {qb4.x, qb4.y, qb4.z, qb4.w}; acc2[ct] = bi; }
    __builtin_amdgcn_s_setprio(1);
    #pragma unroll
    for (int ks = 0; ks < 4; ks++)
      #pragma unroll
      for (int ct = 0; ct < 4; ct++)
        acc2[ct] = __builtin_amdgcn_mfma_f32_16x16x32_bf16(awf[ks], afr[ct][ks], acc2[ct], 0, 0, 0);
    __builtin_amdgcn_s_setprio(0);
    // C: row=feature (quad*4+r), col=token n (ln) -> q[n][d] / k[m][d], d r-consecutive -> b64
    const int base = (rt < 2) ? 0 : KOFFS;
    const int d0   = (rt < 2) ? (rt*16 + quad*4) : ((rt - 2)*16 + quad*4);
    const float sc = (rt < 2) ? (SCALE * LOG2E) : 1.0f;   // fold softmax scale AND log2e into q
    #pragma unroll
    for (int ct = 0; ct < 4; ct++)
      *(unsigned long long*)&hb[base + (ct*16 + ln)*QS + d0] =
          pk4(acc2[ct][0]*sc, acc2[ct][1]*sc, acc2[ct][2]*sc, acc2[ct][3]*sc);
  }

  // ---------------- stage B: S^T = k · q^T, fully batched; softmax batched over 4 ct ----------------
  // exp2 on pre-scaled logits; P stored UNNORMALIZED (values <= ~e, bf16-safe: logits small,
  // mask in {0,-100}); inv[] applied at the O-write in stage C (late normalize).
  float inv[4];
  {
    const float* cw = cmb + (((size_t)(b & 63)*4 + h)*4096) + (ln*4 + quad)*16;
    f32x4 sacc[4][4];   // [ct][rt]  acc-init = combined (mask+rpb)*LOG2E table
    #pragma unroll
    for (int ct = 0; ct < 4; ct++)
      #pragma unroll
      for (int rt = 0; rt < 4; rt++)
        sacc[ct][rt] = *(const f32x4*)(cw + ct*1024 + rt*4);

    bf16x8 ka[4], qb2[4];
    #pragma unroll
    for (int rt = 0; rt < 4; rt++) ka[rt]  = ld8(&hb[KOFFS + (rt*16 + ln)*QS + quad*8]);
    #pragma unroll
    for (int ct = 0; ct < 4; ct++) qb2[ct] = ld8(&hb[(ct*16 + ln)*QS + quad*8]);

    __builtin_amdgcn_s_setprio(1);
    #pragma unroll
    for (int ct = 0; ct < 4; ct++)
      #pragma unroll
      for (int rt = 0; rt < 4; rt++)
        sacc[ct][rt] = __builtin_amdgcn_mfma_f32_16x16x32_bf16(ka[rt], qb2[ct], sacc[ct][rt], 0, 0, 0);
    __builtin_amdgcn_s_setprio(0);

    float s[4] = {0.f, 0.f, 0.f, 0.f};
    #pragma unroll
    for (int ct = 0; ct < 4; ct++)
      #pragma unroll
      for (int rt = 0; rt < 4; rt++)
        #pragma unroll
        for (int r = 0; r < 4; r++) {
          const float e = __builtin_amdgcn_exp2f(sacc[ct][rt][r]);   // m>=49 rows: -1e30 -> 0
          sacc[ct][rt][r] = e;
          s[ct] += e;
        }
    #pragma unroll
    for (int ct = 0; ct < 4; ct++) s[ct] += __shfl_xor(s[ct], 16, 64);
    #pragma unroll
    for (int ct = 0; ct < 4; ct++) s[ct] += __shfl_xor(s[ct], 32, 64);
    #pragma unroll
    for (int ct = 0; ct < 4; ct++) inv[ct] = 1.0f / s[ct];
    // P[n][m] raw e values (m r-consecutive -> b64); aliases own q/k region (per-wave in-order DS)
    #pragma unroll
    for (int ct = 0; ct < 4; ct++)
      #pragma unroll
      for (int rt = 0; rt < 4; rt++)
        *(unsigned long long*)&hb[(ct*16 + ln)*PS + rt*16 + quad*4] =
            pk4(sacc[ct][rt][0], sacc[ct][rt][1], sacc[ct][rt][2], sacc[ct][rt][3]);
  }

  // ---------------- stage C: O^T = v^T · E^T, then scale cols by inv (late normalize) ----------------
  {
    // read ALL P frags first (v^T will overwrite P rows 0..31)
    bf16x8 pb[4][2];
    #pragma unroll
    for (int ct = 0; ct < 4; ct++)
      #pragma unroll
      for (int ks = 0; ks < 2; ks++)
        pb[ct][ks] = ld8(&hb[(ct*16 + ln)*PS + ks*32 + quad*8]);
    // spill held v^T into rows 0..31 (stride VS) — after pb reads (per-wave in-order DS)
    #pragma unroll
    for (int ci = 0; ci < 2; ci++)
      #pragma unroll
      for (int rt = 0; rt < 4; rt++)
        *(unsigned long long*)&hb[(ci*16 + ln)*VS + rt*16 + quad*4] = hv[ci][rt];
    bf16x8 va[2][2];
    #pragma unroll
    for (int rt = 0; rt < 2; rt++)
      #pragma unroll
      for (int ks = 0; ks < 2; ks++)
        va[rt][ks] = ld8(&hb[(rt*16 + ln)*VS + ks*32 + quad*8]);
    f32x4 oacc[2][4];
    #pragma unroll
    for (int rt = 0; rt < 2; rt++)
      #pragma unroll
      for (int ct = 0; ct < 4; ct++) { f32x4 z = {0.f, 0.f, 0.f, 0.f}; oacc[rt][ct] = z; }
    __builtin_amdgcn_s_setprio(1);
    #pragma unroll
    for (int ks = 0; ks < 2; ks++)
      #pragma unroll
      for (int rt = 0; rt < 2; rt++)
        #pragma unroll
        for (int ct = 0; ct < 4; ct++)
          oacc[rt][ct] = __builtin_amdgcn_mfma_f32_16x16x32_bf16(va[rt][ks], pb[ct][ks], oacc[rt][ct], 0, 0, 0);
    __builtin_amdgcn_s_setprio(0);
    // C cols n = ct*16+ln: SAME lane mapping as stage-B's s[ct] -> scale by inv[ct] here.
    // O[n][c-in-head] (c r-consecutive -> b64) into own head's region (overwrites v^T/P; no barrier)
    #pragma unroll
    for (int rt = 0; rt < 2; rt++)
      #pragma unroll
      for (int ct = 0; ct < 4; ct++) {
        const int n = ct*16 + ln;
        if (n < 56)   // rows 56..63 would exceed what's needed; reads of them are dead
          *(unsigned long long*)&hb[n*OS + rt*16 + quad*4] =
              pk4(oacc[rt][ct][0]*inv[ct], oacc[rt][ct][1]*inv[ct],
                  oacc[rt][ct][2]*inv[ct], oacc[rt][ct][3]*inv[ct]);
      }
  }

  // hoist stage-D weight frags + biases ABOVE the barrier: their L2 latency overlaps the
  // barrier wait instead of sitting exposed after it.
  bf16x8 wpa[2][4];
  float4 pb4[2];
  #pragma unroll
  for (int rt = 0; rt < 2; rt++) {
    #pragma unroll
    for (int ks = 0; ks < 4; ks++)
      wpa[rt][ks] = *(const bf16x8*)&pwp[((((h*2 + rt)*4 + ks)*4 + quad)*16 + ln)*8];
    pb4[rt] = *(const float4*)&proj_b[(h*2 + rt)*16 + quad*4];
  }

  __syncthreads();   // the ONLY barrier: O slices complete before cross-head reads

  // ---------------- stage D: out^T = Wproj^T · O^T; float4 global stores ----------------
  {
    bf16x8 ob[4][4];  // [ct: n-tile][ks: c-in 32-chunk] ; chunk ks lives in head-ks's region
    #pragma unroll
    for (int ct = 0; ct < 4; ct++)
      #pragma unroll
      for (int ks = 0; ks < 4; ks++)
        ob[ct][ks] = ld8(&lds[ks*HSZ + (ct*16 + ln)*OS + quad*8]);
    // rows n in 49..63 hold pad/stale-but-finite data; their outputs are discarded below
    float* obp = out + (size_t)b * (NTOK * CDIM);
    #pragma unroll
    for (int rt = 0; rt < 2; rt++) {
      const int c0 = (h*2 + rt)*16 + quad*4;
      f32x4 pacc[4];
      #pragma unroll
      for (int ct = 0; ct < 4; ct++) {
        f32x4 bi = {pb4[rt].x, pb4[rt].y, pb4[rt].z, pb4[rt].w};
        pacc[ct] = bi;
      }
      __builtin_amdgcn_s_setprio(1);
      #pragma unroll
      for (int ks = 0; ks < 4; ks++)
        #pragma unroll
        for (int ct = 0; ct < 4; ct++)
          pacc[ct] = __builtin_amdgcn_mfma_f32_16x16x32_bf16(wpa[rt][ks], ob[ct][ks], pacc[ct], 0, 0, 0);
      __builtin_amdgcn_s_setprio(0);
      #pragma unroll
      for (int ct = 0; ct < 4; ct++) {
        const int n = ct*16 + ln;
        if (n < NTOK) {
          float4 v4;
          v4.x = pacc[ct][0]; v4.y = pacc[ct][1]; v4.z = pacc[ct][2]; v4.w = pacc[ct][3];
          *(float4*)(obp + n*CDIM + c0) = v4;
        }
      }
    }
  }
}

extern "C" void kernel_launch(void* const* d_in, const int* in_sizes, int n_in,
                              void* d_out, int out_size, void* d_ws, size_t ws_size,
                              hipStream_t stream) {
  const float* x          = (const float*)d_in[0];
  const float* mask       = (const float*)d_in[1];
  const float* qkv_w      = (const float*)d_in[2];
  const float* qkv_b      = (const float*)d_in[3];
  const float* proj_w     = (const float*)d_in[4];
  const float* proj_b     = (const float*)d_in[5];
  const float* bias_table = (const float*)d_in[6];
  const int*   rel_index  = (const int*)d_in[7];
  float* out = (float*)d_out;

  char* ws = (char*)d_ws;
  float* cmb            = (float*)ws;
  unsigned short* pwqk  = (unsigned short*)(ws + (size_t)CMB_ELEMS*4);
  unsigned short* pv    = (unsigned short*)(ws + (size_t)CMB_ELEMS*4 + (size_t)PWQK_ELEMS*2);
  unsigned short* pwp   = (unsigned short*)(ws + (size_t)CMB_ELEMS*4 + (size_t)(PWQK_ELEMS + PV_ELEMS)*2);

  // blocks 0..255: cmb (one per (w,h), LDS-staged); blocks 256..511: weight frags (1 elem/thread)
  prep_kernel<<<512, 256, 0, stream>>>(
      mask, qkv_w, proj_w, bias_table, rel_index, cmb, pwqk, pv, pwp);
  win_attn_kernel<<<4096, 256, 0, stream>>>(
      x, qkv_b, proj_b, cmb, pwqk, pv, pwp, out);
}